// Round 7
// baseline (5428.215 us; speedup 1.0000x reference)
//
#include <hip/hip_runtime.h>

// NeuralODE SSP-RK3, z:[32,16,8192] fp32, W:[16,16,5], 100 steps, h=t/100.
// ONE persistent kernel (plain launch), state fp32 in registers for all 100
// steps. Per 5-step round: 15 stages via LDS halo recompute (slab 320 cols =
// 256 interior + 32/side; validity shrinks 2/stage, 30<=32). Round boundary:
// blocks publish 32-col edge tiles to a parity-double-buffered global buffer,
// then PAIRWISE neighbor sync via device-scope atomic flags (no cooperative
// launch — R6's hipLaunchCooperativeKernel silently failed => zero output).
// All 1024 blocks are co-resident by construction (LDS 20.5KB, VGPR<=128 =>
// >=8 blocks/CU capacity), so pairwise spin cannot deadlock.
// Conv = 3x mfma_f32_16x16x32_bf16 per 16-col tile; conv inputs/weights bf16,
// state/pointwise fp32. BC via in-wave shuffles each stage (also quarantines
// wrapped-neighbor halo garbage at domain edges: 2 cols/stage into a 10-wide
// zone reset every stage).

#define NCH    16
#define LL     8192
#define TX     256
#define HALOC  32
#define SLABC  320
#define NBX    32
#define NB     32
#define NSTEPS 100
#define SPK    5
#define NROUND (NSTEPS / SPK)
#define HTILE  (32 * 16)     // floats per side entry: 32 cols x 16 ch

typedef __bf16 bf16x8 __attribute__((ext_vector_type(8)));
typedef __bf16 bf16x4 __attribute__((ext_vector_type(4)));
typedef float  f32x4  __attribute__((ext_vector_type(4)));

__device__ __forceinline__ int ldsIdx(int col, int ch) {
  return col * NCH + (ch ^ ((col & 4) << 1));
}

__device__ __forceinline__ size_t hoff(int parity, int b, int bx, int side) {
  return (size_t)((((parity * NB + b) * NBX + bx) * 2) + side) * HTILE;
}

#define FLAG_STRIDE 16   // one flag per 64B line

__global__ __launch_bounds__(256) void init_kernel(int* flags) {
  const int i = blockIdx.x * 256 + threadIdx.x;
  if (i < NB * NBX * FLAG_STRIDE) flags[i] = 0;
}

__global__ __launch_bounds__(256, 4) void persist_kernel(
    const float* __restrict__ z0,   // row-major [b][ch][x]
    float* __restrict__ out,        // row-major [b][ch][x]
    const float* __restrict__ W,    // [o][i][k] 16x16x5
    const int* __restrict__ tptr,
    float* __restrict__ H,          // halo exchange, 2 parities
    int* __restrict__ flags)        // per-block completed-round counters
{
  __shared__ __align__(16) __bf16 S[2][SLABC * NCH];

  const int blk = blockIdx.x;
  const int b = blk >> 5, bx = blk & 31;
  const int x0 = bx * TX;
  const bool leftE = (bx == 0), rightE = (bx == NBX - 1);
  const float h = (float)(*tptr) / (float)NSTEPS;
  const int tid = threadIdx.x, lane = tid & 63, wv = tid >> 6;
  const int g = lane >> 4, n = lane & 15;
  const int blkL = b * NBX + ((bx + NBX - 1) & 31);
  const int blkR = b * NBX + ((bx + 1) & 31);

  const float* __restrict__ zb = z0 + (size_t)b * NCH * LL;
  float* __restrict__ ob = out + (size_t)b * NCH * LL;

  // Weights -> A fragments (bf16). K-chunk c: taps kk = 2c + (g>>1);
  // lane elems: in-ch i = (g&1)*8 + j; out-ch = n. kk==5 lanes get 0.
  bf16x8 afrag[3];
#pragma unroll
  for (int c = 0; c < 3; ++c) {
    const int kk = c * 2 + (g >> 1);
#pragma unroll
    for (int j = 0; j < 8; ++j) {
      const int i = (g & 1) * 8 + j;
      const float wval = (kk < 5) ? W[n * (NCH * 5) + i * 5 + kk] : 0.0f;
      afrag[c][j] = (__bf16)wval;
    }
  }

  // Initial slab load (row-major source), bf16 into S[0].
  for (int idx = tid; idx < NCH * SLABC; idx += 256) {
    const int ch = idx / SLABC, s = idx - ch * SLABC;
    int gx = x0 - HALOC + s;
    gx = min(max(gx, 0), LL - 1);
    S[0][ldsIdx(s, ch)] = (__bf16)zb[ch * LL + gx];
  }

  // Initial register state: thread owns (x = 16t+n, ch g*4..+3), t = wv+4ti.
  f32x4 kz[5], kf[5];
#pragma unroll
  for (int ti = 0; ti < 5; ++ti) {
    const int t = wv + 4 * ti;
    int gx = x0 - HALOC + 16 * t + n;
    gx = min(max(gx, 0), LL - 1);
#pragma unroll
    for (int r = 0; r < 4; ++r) kz[ti][r] = zb[(size_t)(g * 4 + r) * LL + gx];
    kf[ti] = (f32x4){0.f, 0.f, 0.f, 0.f};
  }
  __syncthreads();

  int hparity = 0;

  // One RK stage. mode 0: LDS store; 1: halo publish; 2: final global store.
  auto stage = [&](float az, float ak, float agh, int rb, bool updZ, int mode) {
    const __bf16* RS = S[rb];
    __bf16* WS = S[rb ^ 1];
#pragma unroll
    for (int ti = 0; ti < 5; ++ti) {
      const int t = wv + 4 * ti;
      f32x4 acc = {0.f, 0.f, 0.f, 0.f};
#pragma unroll
      for (int c = 0; c < 3; ++c) {
        const int kk = c * 2 + (g >> 1);
        int s = 16 * t + n + kk - 2;       // read col = write col + (kk-2)
        s = min(max(s, 0), SLABC - 1);
        bf16x8 bfrag = *(const bf16x8*)(&RS[ldsIdx(s, (g & 1) * 8)]);
        acc = __builtin_amdgcn_mfma_f32_16x16x32_bf16(afrag[c], bfrag, acc, 0, 0, 0);
      }
      f32x4 v;
#pragma unroll
      for (int r = 0; r < 4; ++r)
        v[r] = az * kz[ti][r] + ak * kf[ti][r] + agh * acc[r];

      // BC: x 0..9 <- x=10 (t=2 lane n=10); x 8182..8191 <- x=8181 (t=17 n=5)
      if (leftE && t == 2) {
#pragma unroll
        for (int r = 0; r < 4; ++r) {
          float sv = __shfl(v[r], (lane & 48) | 10, 64);
          if (n < 10) v[r] = sv;
        }
      }
      if (rightE && t == 17) {
#pragma unroll
        for (int r = 0; r < 4; ++r) {
          float sv = __shfl(v[r], (lane & 48) | 5, 64);
          if (n > 5) v[r] = sv;
        }
      }

      kf[ti] = v;
      if (updZ) kz[ti] = v;

      if (mode == 0) {
        bf16x4 bv = { (__bf16)v[0], (__bf16)v[1], (__bf16)v[2], (__bf16)v[3] };
        *(bf16x4*)(&WS[ldsIdx(16 * t + n, g * 4)]) = bv;
      } else if (mode == 1) {
        if (t == 2 || t == 3) {
          *(f32x4*)(H + hoff(hparity, b, bx, 0) + ((t - 2) * 16 + n) * NCH + g * 4) = v;
        } else if (t == 16 || t == 17) {
          *(f32x4*)(H + hoff(hparity, b, bx, 1) + ((t - 16) * 16 + n) * NCH + g * 4) = v;
        }
      } else {  // final store, row-major, interior tiles only
        if (t >= 2 && t <= 17) {
          const int xg = x0 - HALOC + 16 * t + n;
#pragma unroll
          for (int r = 0; r < 4; ++r) ob[(size_t)(g * 4 + r) * LL + xg] = v[r];
        }
      }
    }
  };

  const float c13 = 1.0f / 3.0f, c23 = 2.0f / 3.0f;

#pragma unroll 1
  for (int round = 0; round < NROUND; ++round) {
    hparity = round & 1;
    int rb = 0;
#pragma unroll 1
    for (int sp = 0; sp < SPK; ++sp) {
      const bool last5 = (sp == SPK - 1);
      stage(1.0f, 0.0f, h, rb, false, 0);
      __syncthreads(); rb ^= 1;
      stage(0.75f, 0.25f, 0.25f * h, rb, false, 0);
      __syncthreads(); rb ^= 1;
      if (!last5) {
        stage(c13, c23, c23 * h, rb, true, 0);
        __syncthreads(); rb ^= 1;
      } else {
        stage(c13, c23, c23 * h, rb, true, (round == NROUND - 1) ? 2 : 1);
      }
    }

    if (round < NROUND - 1) {
      // ---- publish: make H writes device-visible, then raise our flag ----
      __threadfence();
      __syncthreads();
      if (tid == 0)
        __hip_atomic_store(&flags[blk * FLAG_STRIDE], round + 1,
                           __ATOMIC_RELEASE, __HIP_MEMORY_SCOPE_AGENT);
      // ---- wait for both neighbors to finish this round ----
      if (tid == 0) {
        const int target = round + 1;
        while (__hip_atomic_load(&flags[blkL * FLAG_STRIDE],
                                 __ATOMIC_ACQUIRE, __HIP_MEMORY_SCOPE_AGENT) < target)
          __builtin_amdgcn_s_sleep(2);
        while (__hip_atomic_load(&flags[blkR * FLAG_STRIDE],
                                 __ATOMIC_ACQUIRE, __HIP_MEMORY_SCOPE_AGENT) < target)
          __builtin_amdgcn_s_sleep(2);
      }
      __syncthreads();
      __threadfence();
      // ---- rebuild S[0]: interior from kz, halos from neighbors' H ----
#pragma unroll
      for (int ti = 0; ti < 5; ++ti) {
        const int t = wv + 4 * ti;
        f32x4 v = kz[ti];
        if (t < 2) {
          v = *(const f32x4*)(H + hoff(hparity, b, (bx + NBX - 1) & 31, 1) +
                              (t * 16 + n) * NCH + g * 4);
          kz[ti] = v;
        } else if (t > 17) {
          v = *(const f32x4*)(H + hoff(hparity, b, (bx + 1) & 31, 0) +
                              ((t - 18) * 16 + n) * NCH + g * 4);
          kz[ti] = v;
        }
        bf16x4 bv = { (__bf16)v[0], (__bf16)v[1], (__bf16)v[2], (__bf16)v[3] };
        *(bf16x4*)(&S[0][ldsIdx(16 * t + n, g * 4)]) = bv;
      }
      __syncthreads();
    }
  }
}

extern "C" void kernel_launch(void* const* d_in, const int* in_sizes, int n_in,
                              void* d_out, int out_size, void* d_ws, size_t ws_size,
                              hipStream_t stream) {
  const float* z0 = (const float*)d_in[0];
  const float* W  = (const float*)d_in[1];
  const int*   t  = (const int*)d_in[2];
  float* out = (float*)d_out;
  float* H   = (float*)d_ws;                         // 8 MiB halo area
  int* flags = (int*)(H + (size_t)2 * NB * NBX * 2 * HTILE);  // +64 KiB flags

  init_kernel<<<dim3((NB * NBX * FLAG_STRIDE + 255) / 256), dim3(256), 0, stream>>>(flags);
  persist_kernel<<<dim3(NB * NBX), dim3(256), 0, stream>>>(z0, out, W, t, H, flags);
}

// Round 8
// 1496.287 us; speedup vs baseline: 3.6278x; 3.6278x over previous
//
#include <hip/hip_runtime.h>

// NeuralODE SSP-RK3, z:[32,16,8192] fp32, W:[16,16,5], 100 steps, h=t/100.
// R5 structure (20 multistep dispatches x 5 fused RK steps; kernel boundary =
// grid barrier — R7 proved atomic-flag sync costs ~260us/round on CDNA4).
// R8 fix: lane-ordered PACKED state layout G[b][tile][lane]*16B (tile = 16
// cols x 16 ch, stored in wave lane order lane=g*16+n <-> (x=16T+n, ch
// 4g..4g+3)). Every state load/store is quarter-wave contiguous -> kills the
// 4x TCC amplification of the old [x][ch] layout (WRITE 76MB -> ~18MB).
// One packed read per thread serves BOTH kz registers and the bf16 LDS slab;
// halos = neighbor's packed tiles (mod-512 wrap; domain-edge garbage is
// BC-quarantined: 2 cols/stage drift into a 10-wide zone reset every stage).
// Conv = 3x mfma_f32_16x16x32_bf16 per 16-col tile (K = tap-pair x 16 in-ch);
// conv inputs/weights bf16, state/pointwise fp32.

#define NCH    16
#define LL     8192
#define TX     256
#define HALOC  32
#define SLABC  320
#define NBX    32
#define NB     32
#define NSTEPS 100
#define SPK    5
#define NKER   (NSTEPS / SPK)
#define NTG    512           // 16-col tiles per batch row

typedef __bf16 bf16x8 __attribute__((ext_vector_type(8)));
typedef __bf16 bf16x4 __attribute__((ext_vector_type(4)));
typedef float  f32x4  __attribute__((ext_vector_type(4)));

__device__ __forceinline__ int ldsIdx(int col, int ch) {
  return col * NCH + (ch ^ ((col & 4) << 1));
}

// packed offset (in floats) of lane's 16B chunk in tile T of batch b
__device__ __forceinline__ size_t goff(int b, int T, int lane) {
  return ((size_t)(b * NTG + T) * 64 + lane) * 4;
}

__global__ __launch_bounds__(256) void pack_kernel(const float* __restrict__ in,
                                                   float* __restrict__ G) {
  const int b = blockIdx.y;
  const int T = blockIdx.x * 4 + (threadIdx.x >> 6);
  const int lane = threadIdx.x & 63, g = lane >> 4, n = lane & 15;
  const float* __restrict__ ib = in + (size_t)b * NCH * LL;
  const int x = T * 16 + n;
  f32x4 v;
#pragma unroll
  for (int r = 0; r < 4; ++r) v[r] = ib[(size_t)(4 * g + r) * LL + x];  // 64B/quarter-wave
  *(f32x4*)(G + goff(b, T, lane)) = v;
}

__global__ __launch_bounds__(256, 4) void multistep_kernel(
    const float* __restrict__ Gin,   // packed state
    float* __restrict__ zout,        // packed state, or row-major d_out if finalKer
    const float* __restrict__ W,     // [o][i][k] 16x16x5
    const int* __restrict__ tptr, int finalKer)
{
  __shared__ __align__(16) __bf16 S[2][SLABC * NCH];

  const int b = blockIdx.y, bx = blockIdx.x;
  const int x0 = bx * TX;
  const bool leftE = (bx == 0), rightE = (bx == NBX - 1);
  const float h = (float)(*tptr) / (float)NSTEPS;
  const int tid = threadIdx.x, lane = tid & 63, wv = tid >> 6;
  const int g = lane >> 4, n = lane & 15;

  // Weights -> A fragments (bf16). K-chunk c: taps kk = 2c + (g>>1);
  // lane elems: in-ch i = (g&1)*8 + j; out-ch = n. kk==5 lanes get 0.
  bf16x8 afrag[3];
#pragma unroll
  for (int c = 0; c < 3; ++c) {
    const int kk = c * 2 + (g >> 1);
#pragma unroll
    for (int j = 0; j < 8; ++j) {
      const int i = (g & 1) * 8 + j;
      const float wval = (kk < 5) ? W[n * (NCH * 5) + i * 5 + kk] : 0.0f;
      afrag[c][j] = (__bf16)wval;
    }
  }

  // One packed read per thread = kz registers + bf16 LDS slab fill.
  // Slab tile t (0..19) <-> global tile (16bx + t - 2) mod 512.
  f32x4 kz[5], kf[5];
#pragma unroll
  for (int ti = 0; ti < 5; ++ti) {
    const int t = wv + 4 * ti;
    const int Tg = (16 * bx + t - 2) & (NTG - 1);
    const f32x4 v = *(const f32x4*)(Gin + goff(b, Tg, lane));
    kz[ti] = v;
    kf[ti] = (f32x4){0.f, 0.f, 0.f, 0.f};
    bf16x4 bv = { (__bf16)v[0], (__bf16)v[1], (__bf16)v[2], (__bf16)v[3] };
    *(bf16x4*)(&S[0][ldsIdx(16 * t + n, g * 4)]) = bv;
  }
  __syncthreads();

  // One RK stage. mode 0: LDS store; 1: packed global store; 2: final row-major.
  auto stage = [&](float az, float ak, float agh, int rb, bool updZ, int mode) {
    const __bf16* RS = S[rb];
    __bf16* WS = S[rb ^ 1];
#pragma unroll
    for (int ti = 0; ti < 5; ++ti) {
      const int t = wv + 4 * ti;
      f32x4 acc = {0.f, 0.f, 0.f, 0.f};
#pragma unroll
      for (int c = 0; c < 3; ++c) {
        const int kk = c * 2 + (g >> 1);
        int s = 16 * t + n + kk - 2;       // read col = write col + (kk-2)
        s = min(max(s, 0), SLABC - 1);
        bf16x8 bfrag = *(const bf16x8*)(&RS[ldsIdx(s, (g & 1) * 8)]);
        acc = __builtin_amdgcn_mfma_f32_16x16x32_bf16(afrag[c], bfrag, acc, 0, 0, 0);
      }
      f32x4 v;
#pragma unroll
      for (int r = 0; r < 4; ++r)
        v[r] = az * kz[ti][r] + ak * kf[ti][r] + agh * acc[r];

      // BC: x 0..9 <- x=10 (t=2 lane n=10); x 8182..8191 <- x=8181 (t=17 n=5)
      if (leftE && t == 2) {
#pragma unroll
        for (int r = 0; r < 4; ++r) {
          float sv = __shfl(v[r], (lane & 48) | 10, 64);
          if (n < 10) v[r] = sv;
        }
      }
      if (rightE && t == 17) {
#pragma unroll
        for (int r = 0; r < 4; ++r) {
          float sv = __shfl(v[r], (lane & 48) | 5, 64);
          if (n > 5) v[r] = sv;
        }
      }

      kf[ti] = v;
      if (updZ) kz[ti] = v;

      if (mode == 0) {
        bf16x4 bv = { (__bf16)v[0], (__bf16)v[1], (__bf16)v[2], (__bf16)v[3] };
        *(bf16x4*)(&WS[ldsIdx(16 * t + n, g * 4)]) = bv;
      } else if (t >= 2 && t <= 17) {
        if (mode == 1) {
          // packed store of block's own 16 tiles (lane-order contiguous)
          *(f32x4*)(zout + goff(b, 16 * bx + t - 2, lane)) = v;
        } else {
          // final row-major store: quarter-wave = 16 consecutive x, 64B lines
          float* __restrict__ ob = zout + (size_t)b * NCH * LL;
          const int xg = x0 - HALOC + 16 * t + n;
#pragma unroll
          for (int r = 0; r < 4; ++r) ob[(size_t)(g * 4 + r) * LL + xg] = v[r];
        }
      }
    }
  };

  const float c13 = 1.0f / 3.0f, c23 = 2.0f / 3.0f;
  int rb = 0;
#pragma unroll 1
  for (int sp = 0; sp < SPK; ++sp) {
    const bool last5 = (sp == SPK - 1);
    stage(1.0f, 0.0f, h, rb, false, 0);
    __syncthreads(); rb ^= 1;
    stage(0.75f, 0.25f, 0.25f * h, rb, false, 0);
    __syncthreads(); rb ^= 1;
    if (!last5) {
      stage(c13, c23, c23 * h, rb, true, 0);
      __syncthreads(); rb ^= 1;
    } else {
      stage(c13, c23, c23 * h, rb, true, finalKer ? 2 : 1);
    }
  }
}

extern "C" void kernel_launch(void* const* d_in, const int* in_sizes, int n_in,
                              void* d_out, int out_size, void* d_ws, size_t ws_size,
                              hipStream_t stream) {
  const float* z0 = (const float*)d_in[0];
  const float* W  = (const float*)d_in[1];
  const int*   t  = (const int*)d_in[2];

  float* Q = (float*)d_out;   // packed intermediates; final row-major dest
  float* P = (float*)d_ws;    // 16 MiB packed scratch

  dim3 grid(NBX, NB), block(256);
  pack_kernel<<<dim3(NTG / 4, NB), block, 0, stream>>>(z0, Q);

  for (int k = 1; k <= NKER; ++k) {
    if (k & 1) multistep_kernel<<<grid, block, 0, stream>>>(Q, P, W, t, 0);
    else       multistep_kernel<<<grid, block, 0, stream>>>(P, Q, W, t, k == NKER);
  }
}